// Round 4
// baseline (32.390 us; speedup 1.0000x reference)
//
#include <hip/hip_runtime.h>

#define NSTEP 32
// DIM = 62 monomials of degree 1..5 over (x0,x1), collapsed per (step,stage)
// into 30 gradient coefficients:
//   g[0..14]  dP/dx0, triangular rows by e0 (widths 5,4,3,2,1; inner Horner in x1)
//   g[15..29] dP/dx1, rows by e1 (inner Horner in x0)
// Table lives in REGISTERS, distributed across the wave's 64 lanes:
//   lane L slot A = task L      (steps 0..15,  stage L&3)
//   lane L slot B = task L+64   (steps 16..31, stage L&3)
// Broadcast per stage via v_readlane (VALU) — no LDS, no global in main loop.

__device__ __forceinline__ float rlane(float v, int l) {
    return __int_as_float(__builtin_amdgcn_readlane(__float_as_int(v), l));
}

__device__ __forceinline__ void collapse(const float* __restrict__ w, float (&out)[30]) {
    float c[6][6];
#pragma unroll
    for (int a = 0; a < 6; ++a)
#pragma unroll
        for (int b = 0; b < 6; ++b) c[a][b] = 0.f;
    // degree-d flat index f: bits of f are the monomial indices; popcount = power of x1
#pragma unroll
    for (int d = 1; d <= 5; ++d)
#pragma unroll
        for (int f = 0; f < (1 << d); ++f) {
            int b = __popc(f);
            c[d - b][b] += w[(1 << d) - 2 + f];
        }
    int k = 0;
#pragma unroll
    for (int e0 = 0; e0 <= 4; ++e0)
#pragma unroll
        for (int e1 = 0; e1 + e0 <= 4; ++e1)
            out[k++] = (float)(e0 + 1) * c[e0 + 1][e1];
#pragma unroll
    for (int e1 = 0; e1 <= 4; ++e1)
#pragma unroll
        for (int e0 = 0; e0 + e1 <= 4; ++e0)
            out[k++] = (float)(e1 + 1) * c[e0][e1 + 1];
}

__device__ __forceinline__ void getg(const float (&tbl)[30], int lanei, float (&g)[30]) {
#pragma unroll
    for (int k = 0; k < 30; ++k) g[k] = rlane(tbl[k], lanei);
}

__device__ __forceinline__ void pgrad(const float (&g)[30], float x0, float x1,
                                      float& d0, float& d1) {
    float r0 = fmaf(fmaf(fmaf(fmaf(g[4], x1, g[3]), x1, g[2]), x1, g[1]), x1, g[0]);
    float r1 = fmaf(fmaf(fmaf(g[8], x1, g[7]), x1, g[6]), x1, g[5]);
    float r2 = fmaf(fmaf(g[11], x1, g[10]), x1, g[9]);
    float r3 = fmaf(g[13], x1, g[12]);
    float r4 = g[14];
    d0 = fmaf(fmaf(fmaf(fmaf(r4, x0, r3), x0, r2), x0, r1), x0, r0);

    float s0 = fmaf(fmaf(fmaf(fmaf(g[19], x0, g[18]), x0, g[17]), x0, g[16]), x0, g[15]);
    float s1 = fmaf(fmaf(fmaf(g[23], x0, g[22]), x0, g[21]), x0, g[20]);
    float s2 = fmaf(fmaf(g[26], x0, g[25]), x0, g[24]);
    float s3 = fmaf(g[28], x0, g[27]);
    float s4 = g[29];
    d1 = fmaf(fmaf(fmaf(fmaf(s4, x1, s3), x1, s2), x1, s1), x1, s0);
}

__device__ __forceinline__ void dostep_rl(const float (&tbl)[30], int base,
                                          float& q0, float& q1, float& p0, float& p1,
                                          float dt, float hdt) {
    float g[30];

    getg(tbl, base + 0, g);                       // A
    float dA0, dA1; pgrad(g, p0, p1, dA0, dA1);
    q0 = fmaf(dA0, hdt, q0); q1 = fmaf(dA1, hdt, q1);

    getg(tbl, base + 1, g);                       // B
    float dB0, dB1; pgrad(g, q0, q1, dB0, dB1);
    p0 = fmaf(-dB0, dt, p0); p1 = fmaf(-dB1, dt, p1);
    q0 = fmaf(dA0, hdt, q0); q1 = fmaf(dA1, hdt, q1);

    float u0 = q1, u1 = p0, v0 = q0, v1 = p1;

    getg(tbl, base + 2, g);                       // C
    float dC0, dC1; pgrad(g, v0, v1, dC0, dC1);
    u0 = fmaf(dC1, hdt, u0); u1 = fmaf(-dC0, hdt, u1);

    getg(tbl, base + 3, g);                       // D
    float dD0, dD1; pgrad(g, u0, u1, dD0, dD1);
    v0 = fmaf(dD1, dt, v0); v1 = fmaf(-dD0, dt, v1);
    u0 = fmaf(dC1, hdt, u0); u1 = fmaf(-dC0, hdt, u1);

    q0 = v0; q1 = u0; p0 = u1; p1 = v1;           // z = [v0, u0, u1, v1]
}

__device__ __forceinline__ const float* wsel(const float* A, const float* B,
                                             const float* C, const float* D, int t) {
    int which = t & 3, stepi = t >> 2;
    const float* w = (which == 0) ? A : (which == 1) ? B : (which == 2) ? C : D;
    return w + stepi * 62;
}

__global__ void __launch_bounds__(256, 1)
sympl_rl(const float* __restrict__ zin,
         const float* __restrict__ Aw, const float* __restrict__ Bw,
         const float* __restrict__ Cw, const float* __restrict__ Dw,
         const int* __restrict__ nsp,
         float* __restrict__ zout, int batch) {
    int lt = threadIdx.x;
    int idx = blockIdx.x * 256 + lt;
    int lane = lt & 63;
    bool active = idx < batch;

    float4 zv = make_float4(0.f, 0.f, 0.f, 0.f);
    if (active) zv = reinterpret_cast<const float4*>(zin)[idx];
    float dt  = 1.0f / (32.0f * (float)nsp[0]);
    float hdt = 0.5f * dt;

    // ---- per-lane prep: collapse tasks (lane) and (lane+64) into registers ----
    float tA[30], tB[30];
    collapse(wsel(Aw, Bw, Cw, Dw, lane), tA);
    collapse(wsel(Aw, Bw, Cw, Dw, lane + 64), tB);

    float q0 = zv.x, q1 = zv.y, p0 = zv.z, p1 = zv.w;

    // ---- main loop: pure VALU, coefficients broadcast via v_readlane ----
#pragma unroll 1
    for (int s = 0; s < NSTEP; ++s) {
        if (s < 16) {
            dostep_rl(tA, 4 * s, q0, q1, p0, p1, dt, hdt);
        } else {
            dostep_rl(tB, 4 * (s - 16), q0, q1, p0, p1, dt, hdt);
        }
    }

    if (active) {
        float4 o; o.x = q0; o.y = q1; o.z = p0; o.w = p1;
        reinterpret_cast<float4*>(zout)[idx] = o;
    }
}

extern "C" void kernel_launch(void* const* d_in, const int* in_sizes, int n_in,
                              void* d_out, int out_size, void* d_ws, size_t ws_size,
                              hipStream_t stream) {
    const float* z  = (const float*)d_in[0];
    const float* Aw = (const float*)d_in[1];
    const float* Bw = (const float*)d_in[2];
    const float* Cw = (const float*)d_in[3];
    const float* Dw = (const float*)d_in[4];
    const int*   ns = (const int*)d_in[5];

    int batch = in_sizes[0] / 4;
    int threads = 256;
    int blocks = (batch + threads - 1) / threads;
    sympl_rl<<<blocks, threads, 0, stream>>>(z, Aw, Bw, Cw, Dw, ns,
                                             (float*)d_out, batch);
}